// Round 3
// baseline (1556.787 us; speedup 1.0000x reference)
//
#include <hip/hip_runtime.h>

#define NN 50000
#define NE 400000
#define NFD 320

typedef short bf16x8 __attribute__((ext_vector_type(8)));
typedef float f32x4 __attribute__((ext_vector_type(4)));

__device__ __forceinline__ unsigned short f2bf(float f){
  unsigned int u = __float_as_uint(f);
  u += 0x7fffu + ((u >> 16) & 1u);
  return (unsigned short)(u >> 16);
}
__device__ __forceinline__ float bflo(unsigned int q){ return __uint_as_float(q << 16); }
__device__ __forceinline__ float bfhi(unsigned int q){ return __uint_as_float(q & 0xffff0000u); }
__device__ __forceinline__ float silu_f(float x){ return x / (1.f + __expf(-x)); }

// Pack weight W [320][kstride] (f32, row-major) into MFMA B-fragment order:
// P[((ct*KS + ks)*64 + lane)*8 + e] = bf16( W[ct*16 + (lane&15)][ks*32 + 8*(lane>>4) + e] )
__global__ void pack_w(const float* __restrict__ W, unsigned short* __restrict__ P,
                       int kstride, int KS){
  int idx = blockIdx.x * 256 + threadIdx.x;
  if (idx >= 20 * KS * 64) return;
  int lane = idx & 63;
  int t  = idx >> 6;
  int ks = t % KS;
  int ct = t / KS;
  const float* src = W + (size_t)(ct*16 + (lane & 15)) * kstride + ks*32 + 8*(lane >> 4);
  unsigned int q[4];
  #pragma unroll
  for (int j = 0; j < 4; j++){
    unsigned int a = f2bf(src[2*j]);
    unsigned int b = f2bf(src[2*j+1]);
    q[j] = a | (b << 16);
  }
  *(uint4*)(P + (size_t)idx * 8) = make_uint4(q[0], q[1], q[2], q[3]);
}

__global__ void extract_last(const float* __restrict__ W, float* __restrict__ out){
  int o = threadIdx.x;           // 320 threads
  out[o] = W[(size_t)o * 641 + 640];
}

// h (f32) -> bf16, once
__global__ void h2bf(const float* __restrict__ h, unsigned short* __restrict__ hbf){
  int i = blockIdx.x * 256 + threadIdx.x;   // one float4 per thread
  float4 v = *(const float4*)(h + (size_t)i * 4);
  unsigned int lo = (unsigned int)f2bf(v.x) | ((unsigned int)f2bf(v.y) << 16);
  unsigned int hi = (unsigned int)f2bf(v.z) | ((unsigned int)f2bf(v.w) << 16);
  *(uint2*)(hbf + (size_t)i * 4) = make_uint2(lo, hi);
}

__global__ void cinit(const float* __restrict__ coord, float* __restrict__ outc){
  int i = blockIdx.x * 256 + threadIdx.x;
  if (i < NN*3) outc[i] = coord[i];
}

// ---- CSR build: histogram, 1-block scan, scatter ----
__global__ void hist_k(const int* __restrict__ ei, int* __restrict__ cnt){
  int e = blockIdx.x * 256 + threadIdx.x;
  if (e < NE) atomicAdd(&cnt[ei[e]], 1);
}

__global__ void __launch_bounds__(1024)
scan_k(const int* __restrict__ cnt, int* __restrict__ cur){
  __shared__ int part[1024];
  const int tid = threadIdx.x;
  const int per = (NN + 1023) / 1024;   // 49
  const int base = tid * per;
  int s = 0;
  for (int i = 0; i < per; i++){
    int j = base + i;
    if (j < NN) s += cnt[j];
  }
  part[tid] = s;
  __syncthreads();
  for (int d = 1; d < 1024; d <<= 1){
    int v = (tid >= d) ? part[tid - d] : 0;
    __syncthreads();
    part[tid] += v;
    __syncthreads();
  }
  int pre = (tid > 0) ? part[tid - 1] : 0;
  for (int i = 0; i < per; i++){
    int j = base + i;
    if (j < NN){
      cur[j] = pre;
      pre += cnt[j];
    }
  }
}

__global__ void scatter_k(const int* __restrict__ ei, int* __restrict__ cur,
                          int* __restrict__ perm){
  int e = blockIdx.x * 256 + threadIdx.x;
  if (e < NE){
    int p = atomicAdd(&cur[ei[e]], 1);
    perm[p] = e;
  }
}

// ---------------- edge kernel: 32 sorted edges/block, 256 threads ----------------
__global__ void __launch_bounds__(256, 3)
edge_kernel(const unsigned short* __restrict__ hbf, const float* __restrict__ coord,
            const int* __restrict__ ei, const int* __restrict__ perm,
            const unsigned short* __restrict__ We1p, const float* __restrict__ we1l,
            const float* __restrict__ be1,
            const unsigned short* __restrict__ We2p, const float* __restrict__ be2,
            const unsigned short* __restrict__ Wc1p, const float* __restrict__ bc1,
            const float* __restrict__ Wc2,
            unsigned short* __restrict__ agg, float* __restrict__ cacc)
{
  __shared__ __align__(16) unsigned short s_x[32*328]; // staged input half / m2
  __shared__ __align__(16) unsigned short s_m[32*328]; // m1 / c1
  __shared__ float4 s_cd[32];
  __shared__ int s_row[32];
  __shared__ int s_col[32];
  __shared__ float s_w[32];

  const int tid  = threadIdx.x;
  const int lane = tid & 63;
  const int wv   = tid >> 6;     // 0..3 = column chunk
  const int e0   = blockIdx.x * 32;

  if (tid < 32){
    int e = perm[e0 + tid];
    int r = ei[e];
    int c = ei[NE + e];
    s_row[tid] = r; s_col[tid] = c;
    float dx = coord[r*3+0] - coord[c*3+0];
    float dy = coord[r*3+1] - coord[c*3+1];
    float dz = coord[r*3+2] - coord[c*3+2];
    float rad = dx*dx + dy*dy + dz*dz;
    float inv = 1.f / (sqrtf(rad) + 1e-8f);
    s_cd[tid] = make_float4(dx*inv, dy*inv, dz*inv, rad);
  }
  __syncthreads();

  const int ch = wv;                    // columns ch*80 .. ch*80+79 (5 tiles of 16)
  const int arow0 = (lane & 15);        // row-tile 0
  const int arow1 = 16 + (lane & 15);   // row-tile 1
  const int kl = 8 * (lane >> 4);
  const int rb = (lane >> 4) * 4;       // acc row base within tile

  f32x4 acc[2][5];
  #pragma unroll
  for (int rt = 0; rt < 2; rt++)
    #pragma unroll
    for (int t = 0; t < 5; t++) acc[rt][t] = {0.f,0.f,0.f,0.f};

  // ---- stage h[row] half (pure bf16 copy: 32 rows x 40 uint4 chunks) ----
  #pragma unroll
  for (int i = 0; i < 5; i++){
    int idx = tid + i*256;
    int r = idx / 40;
    int c = idx - r*40;
    uint4 v = *(const uint4*)(hbf + (size_t)s_row[r]*NFD + c*8);
    *(uint4*)(s_x + r*328 + c*8) = v;
  }
  __syncthreads();

  // ---- L1 half0: ks 0..9 (h[row] part) ----
  for (int ks = 0; ks < 10; ks++){
    bf16x8 a0 = *(const bf16x8*)(s_x + arow0*328 + ks*32 + kl);
    bf16x8 a1 = *(const bf16x8*)(s_x + arow1*328 + ks*32 + kl);
    #pragma unroll
    for (int t = 0; t < 5; t++){
      bf16x8 b = *(const bf16x8*)(We1p + ((size_t)((ch*5 + t)*20 + ks)*64 + lane)*8);
      acc[0][t] = __builtin_amdgcn_mfma_f32_16x16x32_bf16(a0, b, acc[0][t], 0, 0, 0);
      acc[1][t] = __builtin_amdgcn_mfma_f32_16x16x32_bf16(a1, b, acc[1][t], 0, 0, 0);
    }
  }
  __syncthreads();

  // ---- stage h[col] half ----
  #pragma unroll
  for (int i = 0; i < 5; i++){
    int idx = tid + i*256;
    int r = idx / 40;
    int c = idx - r*40;
    uint4 v = *(const uint4*)(hbf + (size_t)s_col[r]*NFD + c*8);
    *(uint4*)(s_x + r*328 + c*8) = v;
  }
  __syncthreads();

  // ---- L1 half1: ks 10..19 (h[col] part), + radial/bias epilogue -> m1 in s_m ----
  for (int ks = 0; ks < 10; ks++){
    bf16x8 a0 = *(const bf16x8*)(s_x + arow0*328 + ks*32 + kl);
    bf16x8 a1 = *(const bf16x8*)(s_x + arow1*328 + ks*32 + kl);
    #pragma unroll
    for (int t = 0; t < 5; t++){
      bf16x8 b = *(const bf16x8*)(We1p + ((size_t)((ch*5 + t)*20 + 10 + ks)*64 + lane)*8);
      acc[0][t] = __builtin_amdgcn_mfma_f32_16x16x32_bf16(a0, b, acc[0][t], 0, 0, 0);
      acc[1][t] = __builtin_amdgcn_mfma_f32_16x16x32_bf16(a1, b, acc[1][t], 0, 0, 0);
    }
  }
  #pragma unroll
  for (int rt = 0; rt < 2; rt++){
    #pragma unroll
    for (int t = 0; t < 5; t++){
      int o = (ch*5 + t)*16 + (lane & 15);
      float wl = we1l[o];
      float bb = be1[o];
      #pragma unroll
      for (int r = 0; r < 4; r++){
        int er = rt*16 + rb + r;
        float v = silu_f(acc[rt][t][r] + s_cd[er].w * wl + bb);
        s_m[er*328 + o] = f2bf(v);
      }
    }
  }
  __syncthreads();

  // ---- L2: m2 = silu(m1 @ We2^T + be2) -> s_x ----
  #pragma unroll
  for (int rt = 0; rt < 2; rt++)
    #pragma unroll
    for (int t = 0; t < 5; t++) acc[rt][t] = {0.f,0.f,0.f,0.f};
  for (int ks = 0; ks < 10; ks++){
    bf16x8 a0 = *(const bf16x8*)(s_m + arow0*328 + ks*32 + kl);
    bf16x8 a1 = *(const bf16x8*)(s_m + arow1*328 + ks*32 + kl);
    #pragma unroll
    for (int t = 0; t < 5; t++){
      bf16x8 b = *(const bf16x8*)(We2p + ((size_t)((ch*5 + t)*10 + ks)*64 + lane)*8);
      acc[0][t] = __builtin_amdgcn_mfma_f32_16x16x32_bf16(a0, b, acc[0][t], 0, 0, 0);
      acc[1][t] = __builtin_amdgcn_mfma_f32_16x16x32_bf16(a1, b, acc[1][t], 0, 0, 0);
    }
  }
  __syncthreads();
  #pragma unroll
  for (int rt = 0; rt < 2; rt++){
    #pragma unroll
    for (int t = 0; t < 5; t++){
      int o = (ch*5 + t)*16 + (lane & 15);
      float bb = be2[o];
      #pragma unroll
      for (int r = 0; r < 4; r++){
        int er = rt*16 + rb + r;
        float v = silu_f(acc[rt][t][r] + bb);
        s_x[er*328 + o] = f2bf(v);
      }
    }
  }
  __syncthreads();

  // ---- c1 = silu(m2 @ Wc1^T + bc1) -> s_m ----
  #pragma unroll
  for (int rt = 0; rt < 2; rt++)
    #pragma unroll
    for (int t = 0; t < 5; t++) acc[rt][t] = {0.f,0.f,0.f,0.f};
  for (int ks = 0; ks < 10; ks++){
    bf16x8 a0 = *(const bf16x8*)(s_x + arow0*328 + ks*32 + kl);
    bf16x8 a1 = *(const bf16x8*)(s_x + arow1*328 + ks*32 + kl);
    #pragma unroll
    for (int t = 0; t < 5; t++){
      bf16x8 b = *(const bf16x8*)(Wc1p + ((size_t)((ch*5 + t)*10 + ks)*64 + lane)*8);
      acc[0][t] = __builtin_amdgcn_mfma_f32_16x16x32_bf16(a0, b, acc[0][t], 0, 0, 0);
      acc[1][t] = __builtin_amdgcn_mfma_f32_16x16x32_bf16(a1, b, acc[1][t], 0, 0, 0);
    }
  }
  #pragma unroll
  for (int rt = 0; rt < 2; rt++){
    #pragma unroll
    for (int t = 0; t < 5; t++){
      int o = (ch*5 + t)*16 + (lane & 15);
      float bb = bc1[o];
      #pragma unroll
      for (int r = 0; r < 4; r++){
        int er = rt*16 + rb + r;
        float v = silu_f(acc[rt][t][r] + bb);
        s_m[er*328 + o] = f2bf(v);
      }
    }
  }
  __syncthreads();

  // ---- w = c1 . Wc2 (8 threads/edge) -> s_w ----
  {
    int e = tid >> 3;            // 0..31
    int j = tid & 7;
    const float* w8 = Wc2 + j*40;
    float sum = 0.f;
    #pragma unroll
    for (int u = 0; u < 5; u++){
      uint4 q = *(const uint4*)(s_m + e*328 + j*40 + u*8);
      const float* w = w8 + u*8;
      sum += bflo(q.x)*w[0] + bfhi(q.x)*w[1] + bflo(q.y)*w[2] + bfhi(q.y)*w[3]
           + bflo(q.z)*w[4] + bfhi(q.z)*w[5] + bflo(q.w)*w[6] + bfhi(q.w)*w[7];
    }
    sum += __shfl_xor(sum, 1);
    sum += __shfl_xor(sum, 2);
    sum += __shfl_xor(sum, 4);
    if (j == 0) s_w[e] = sum;
  }
  __syncthreads();

  // ---- segmented reduce of m2 (s_x, rows sorted by s_row) -> agg flush atomics ----
  if (tid < 160){
    int p = tid;                 // column pair: columns 2p, 2p+1
    float a0 = 0.f, a1 = 0.f;
    #pragma unroll
    for (int e = 0; e < 32; e++){
      unsigned int q = *(const unsigned int*)(s_x + e*328 + p*2);
      a0 += bflo(q); a1 += bfhi(q);
      if (e == 31 || s_row[e+1] != s_row[e]){
        unsigned int val = (unsigned int)f2bf(a0) | ((unsigned int)f2bf(a1) << 16);
        unsigned short* dst = agg + (size_t)s_row[e]*NFD + p*2;
        asm volatile("global_atomic_pk_add_bf16 %0, %1, off" :: "v"(dst), "v"(val) : "memory");
        a0 = 0.f; a1 = 0.f;
      }
    }
  }

  // ---- segmented reduce of coord trans (wave 3, lanes 0..2) ----
  if (tid >= 192 && tid < 195){
    int d = tid - 192;
    float a = 0.f;
    #pragma unroll
    for (int e = 0; e < 32; e++){
      float cdc = (d == 0) ? s_cd[e].x : (d == 1) ? s_cd[e].y : s_cd[e].z;
      a += cdc * s_w[e];
      if (e == 31 || s_row[e+1] != s_row[e]){
        atomicAdd(cacc + (size_t)s_row[e]*3 + d, a);
        a = 0.f;
      }
    }
  }
}

// ---------------- node kernel: 32 nodes/block, 256 threads, 3 blocks/CU ----------------
__global__ void __launch_bounds__(256, 3)
node_kernel(const float* __restrict__ h, const unsigned short* __restrict__ agg,
            const unsigned short* __restrict__ Wn1p, const float* __restrict__ bn1,
            const unsigned short* __restrict__ Wn2p, const float* __restrict__ bn2,
            float* __restrict__ hout)
{
  __shared__ __align__(16) unsigned short s_x[32*328];
  __shared__ __align__(16) unsigned short s_m[32*328];

  const int tid  = threadIdx.x;
  const int lane = tid & 63;
  const int wv   = tid >> 6;
  const int n0   = blockIdx.x * 32;

  const int rt = wv & 1;
  const int ch = wv >> 1;
  const int r0 = rt * 16;
  const int arow = r0 + (lane & 15);
  const int kl = 8 * (lane >> 4);
  const int colbase = ch * 160;
  const int rbase = r0 + (lane >> 4)*4;

  f32x4 acc[10];
  #pragma unroll
  for (int t = 0; t < 10; t++) acc[t] = {0.f,0.f,0.f,0.f};

  // ---- stage h (f32 -> bf16): 32 rows x 80 float4 ----
  #pragma unroll
  for (int i = 0; i < 10; i++){
    int idx = tid + i*256;
    int r = idx / 80;
    int c = idx - r*80;
    int node = n0 + r;
    float4 v = (node < NN) ? *(const float4*)(h + (size_t)node*NFD + c*4)
                           : make_float4(0,0,0,0);
    unsigned int lo = (unsigned int)f2bf(v.x) | ((unsigned int)f2bf(v.y) << 16);
    unsigned int hi = (unsigned int)f2bf(v.z) | ((unsigned int)f2bf(v.w) << 16);
    *(uint2*)(s_x + r*328 + c*4) = make_uint2(lo, hi);
  }
  __syncthreads();

  // ---- n1 half0 (h part): ks 0..9 ----
  for (int ks = 0; ks < 10; ks++){
    bf16x8 a = *(const bf16x8*)(s_x + arow*328 + ks*32 + kl);
    #pragma unroll
    for (int t = 0; t < 10; t++){
      bf16x8 b = *(const bf16x8*)(Wn1p + ((size_t)((ch*10 + t)*20 + ks)*64 + lane)*8);
      acc[t] = __builtin_amdgcn_mfma_f32_16x16x32_bf16(a, b, acc[t], 0, 0, 0);
    }
  }
  __syncthreads();

  // ---- stage agg (bf16 copy): 32 rows x 40 uint4 ----
  #pragma unroll
  for (int i = 0; i < 5; i++){
    int idx = tid + i*256;
    int r = idx / 40;
    int c = idx - r*40;
    int node = n0 + r;
    uint4 v = (node < NN) ? *(const uint4*)(agg + (size_t)node*NFD + c*8)
                          : make_uint4(0,0,0,0);
    *(uint4*)(s_x + r*328 + c*8) = v;
  }
  __syncthreads();

  // ---- n1 half1 (agg part): ks 10..19, silu -> s_m ----
  for (int ks = 0; ks < 10; ks++){
    bf16x8 a = *(const bf16x8*)(s_x + arow*328 + ks*32 + kl);
    #pragma unroll
    for (int t = 0; t < 10; t++){
      bf16x8 b = *(const bf16x8*)(Wn1p + ((size_t)((ch*10 + t)*20 + 10 + ks)*64 + lane)*8);
      acc[t] = __builtin_amdgcn_mfma_f32_16x16x32_bf16(a, b, acc[t], 0, 0, 0);
    }
  }
  #pragma unroll
  for (int t = 0; t < 10; t++){
    int o = colbase + t*16 + (lane & 15);
    float bb = bn1[o];
    #pragma unroll
    for (int r = 0; r < 4; r++){
      float v = silu_f(acc[t][r] + bb);
      s_m[(rbase + r)*328 + o] = f2bf(v);
    }
  }
  __syncthreads();

  // ---- n2: out = hid @ Wn2^T + bn2 + h (residual), straight to global ----
  #pragma unroll
  for (int t = 0; t < 10; t++) acc[t] = {0.f,0.f,0.f,0.f};
  for (int ks = 0; ks < 10; ks++){
    bf16x8 a = *(const bf16x8*)(s_m + arow*328 + ks*32 + kl);
    #pragma unroll
    for (int t = 0; t < 10; t++){
      bf16x8 b = *(const bf16x8*)(Wn2p + ((size_t)((ch*10 + t)*10 + ks)*64 + lane)*8);
      acc[t] = __builtin_amdgcn_mfma_f32_16x16x32_bf16(a, b, acc[t], 0, 0, 0);
    }
  }
  #pragma unroll
  for (int t = 0; t < 10; t++){
    int o = colbase + t*16 + (lane & 15);
    float bb = bn2[o];
    #pragma unroll
    for (int r = 0; r < 4; r++){
      int node = n0 + rbase + r;
      if (node < NN){
        hout[(size_t)node*NFD + o] = h[(size_t)node*NFD + o] + acc[t][r] + bb;
      }
    }
  }
}

extern "C" void kernel_launch(void* const* d_in, const int* in_sizes, int n_in,
                              void* d_out, int out_size, void* d_ws, size_t ws_size,
                              hipStream_t stream){
  const float* h     = (const float*)d_in[0];
  const float* coord = (const float*)d_in[1];
  const int*   ei    = (const int*)d_in[2];
  const float* We1 = (const float*)d_in[3];
  const float* be1 = (const float*)d_in[4];
  const float* We2 = (const float*)d_in[5];
  const float* be2 = (const float*)d_in[6];
  const float* Wn1 = (const float*)d_in[7];
  const float* bn1 = (const float*)d_in[8];
  const float* Wn2 = (const float*)d_in[9];
  const float* bn2 = (const float*)d_in[10];
  const float* Wc1 = (const float*)d_in[11];
  const float* bc1 = (const float*)d_in[12];
  const float* Wc2 = (const float*)d_in[13];

  char* ws = (char*)d_ws;
  unsigned short* We1p = (unsigned short*)(ws);             // 409600 B
  unsigned short* We2p = (unsigned short*)(ws + 409600);    // 204800 B
  unsigned short* Wc1p = (unsigned short*)(ws + 614400);    // 204800 B
  unsigned short* Wn1p = (unsigned short*)(ws + 819200);    // 409600 B
  unsigned short* Wn2p = (unsigned short*)(ws + 1228800);   // 204800 B
  float*          we1l = (float*)(ws + 1433600);            // 1280 B
  unsigned short* agg  = (unsigned short*)(ws + 1434880);   // 32,000,000 B
  int*            cnt  = (int*)(ws + 33434880);             // 200,000 B
  int*            cur  = (int*)(ws + 33634880);             // 200,000 B
  int*            perm = (int*)(ws + 33834880);             // 1,600,000 B

  float* hout = (float*)d_out;
  float* cout = hout + (size_t)NN * NFD;        // coord output region
  // h_bf lives in the (dead until node_kernel) hout region: 32 MB of 64 MB
  unsigned short* hbf = (unsigned short*)d_out;

  hipMemsetAsync(agg, 0, (size_t)NN * NFD * 2, stream);
  hipMemsetAsync(cnt, 0, (size_t)NN * 4, stream);

  h2bf<<<NN*NFD/4/256, 256, 0, stream>>>(h, hbf);
  cinit<<<(NN*3 + 255)/256, 256, 0, stream>>>(coord, cout);

  pack_w<<<100, 256, 0, stream>>>(We1, We1p, 641, 20);
  pack_w<<< 50, 256, 0, stream>>>(We2, We2p, 320, 10);
  pack_w<<< 50, 256, 0, stream>>>(Wc1, Wc1p, 320, 10);
  pack_w<<<100, 256, 0, stream>>>(Wn1, Wn1p, 640, 20);
  pack_w<<< 50, 256, 0, stream>>>(Wn2, Wn2p, 320, 10);
  extract_last<<<1, 320, 0, stream>>>(We1, we1l);

  hist_k<<<(NE + 255)/256, 256, 0, stream>>>(ei, cnt);
  scan_k<<<1, 1024, 0, stream>>>(cnt, cur);
  scatter_k<<<(NE + 255)/256, 256, 0, stream>>>(ei, cur, perm);

  edge_kernel<<<NE/32, 256, 0, stream>>>(hbf, coord, ei, perm, We1p, we1l, be1,
                                         We2p, be2, Wc1p, bc1, Wc2, agg, cout);
  node_kernel<<<(NN + 31)/32, 256, 0, stream>>>(h, agg, Wn1p, bn1, Wn2p, bn2, hout);
}

// Round 4
// 643.523 us; speedup vs baseline: 2.4192x; 2.4192x over previous
//
#include <hip/hip_runtime.h>

#define NN 50000
#define NE 400000
#define NFD 320
#define NB1 196   // ceil(NN/256)

typedef short bf16x8 __attribute__((ext_vector_type(8)));
typedef float f32x4 __attribute__((ext_vector_type(4)));

#define MFMA16 __builtin_amdgcn_mfma_f32_16x16x32_bf16

__device__ __forceinline__ unsigned short f2bf(float f){
  unsigned int u = __float_as_uint(f);
  u += 0x7fffu + ((u >> 16) & 1u);
  return (unsigned short)(u >> 16);
}
__device__ __forceinline__ float bflo(unsigned int q){ return __uint_as_float(q << 16); }
__device__ __forceinline__ float bfhi(unsigned int q){ return __uint_as_float(q & 0xffff0000u); }
__device__ __forceinline__ float silu_f(float x){ return x / (1.f + __expf(-x)); }

// Pack weight W [320][kstride] (f32, row-major) into MFMA B-fragment order:
// P[(ct*KS + ks)*512 + lane*8 + e] = bf16( W[ct*16+(lane&15)][ks*32 + 8*(lane>>4) + e] )
__global__ void pack_w(const float* __restrict__ W, unsigned short* __restrict__ P,
                       int kstride, int KS){
  int idx = blockIdx.x * 256 + threadIdx.x;
  if (idx >= 20 * KS * 64) return;
  int lane = idx & 63;
  int t  = idx >> 6;
  int ks = t % KS;
  int ct = t / KS;
  const float* src = W + (size_t)(ct*16 + (lane & 15)) * kstride + ks*32 + 8*(lane >> 4);
  unsigned int q[4];
  #pragma unroll
  for (int j = 0; j < 4; j++){
    unsigned int a = f2bf(src[2*j]);
    unsigned int b = f2bf(src[2*j+1]);
    q[j] = a | (b << 16);
  }
  *(uint4*)(P + (size_t)idx * 8) = make_uint4(q[0], q[1], q[2], q[3]);
}

// Pack stacked [W_r; W_c] (from We1 [320][641]) -> 40 ct-tiles x 10 ks
__global__ void pack_stack(const float* __restrict__ We1, unsigned short* __restrict__ P){
  int idx = blockIdx.x * 256 + threadIdx.x;
  if (idx >= 40 * 10 * 64) return;
  int lane = idx & 63;
  int t  = idx >> 6;
  int ks = t % 10;
  int ct = t / 10;                       // 0..39
  int o  = ct*16 + (lane & 15);          // 0..639
  int k  = ks*32 + 8*(lane >> 4);
  const float* src = (o < 320) ? (We1 + (size_t)o * 641 + k)
                               : (We1 + (size_t)(o - 320) * 641 + 320 + k);
  unsigned int q[4];
  #pragma unroll
  for (int j = 0; j < 4; j++){
    unsigned int a = f2bf(src[2*j]);
    unsigned int b = f2bf(src[2*j+1]);
    q[j] = a | (b << 16);
  }
  *(uint4*)(P + (size_t)idx * 8) = make_uint4(q[0], q[1], q[2], q[3]);
}

__global__ void extract_last(const float* __restrict__ W, float* __restrict__ out){
  int o = threadIdx.x;           // 320 threads
  out[o] = W[(size_t)o * 641 + 640];
}

__global__ void cinit(const float* __restrict__ coord, float* __restrict__ outc){
  int i = blockIdx.x * 256 + threadIdx.x;
  if (i < NN*3) outc[i] = coord[i];
}

// ---- CSR build: histogram, coalesced 3-phase scan, scatter ----
__global__ void hist_k(const int* __restrict__ ei, int* __restrict__ cnt){
  int e = blockIdx.x * 256 + threadIdx.x;
  if (e < NE) atomicAdd(&cnt[ei[e]], 1);
}

__global__ void scan1(const int* __restrict__ cnt, int* __restrict__ cur,
                      int* __restrict__ bsum){
  __shared__ int sh[256];
  int tid = threadIdx.x;
  int i = blockIdx.x * 256 + tid;
  int v = (i < NN) ? cnt[i] : 0;
  sh[tid] = v;
  __syncthreads();
  for (int d = 1; d < 256; d <<= 1){
    int u = (tid >= d) ? sh[tid - d] : 0;
    __syncthreads();
    sh[tid] += u;
    __syncthreads();
  }
  if (i < NN) cur[i] = sh[tid] - v;            // exclusive within block
  if (tid == 255) bsum[blockIdx.x] = sh[255];  // block total
}

__global__ void scan2(int* __restrict__ bsum){
  __shared__ int sh[256];
  int tid = threadIdx.x;
  int v = (tid < NB1) ? bsum[tid] : 0;
  sh[tid] = v;
  __syncthreads();
  for (int d = 1; d < 256; d <<= 1){
    int u = (tid >= d) ? sh[tid - d] : 0;
    __syncthreads();
    sh[tid] += u;
    __syncthreads();
  }
  if (tid < NB1) bsum[tid] = sh[tid] - v;      // exclusive block offsets
}

__global__ void scan3(int* __restrict__ cur, const int* __restrict__ bsum){
  int i = blockIdx.x * 256 + threadIdx.x;
  if (i < NN) cur[i] += bsum[blockIdx.x];
}

__global__ void scatter_k(const int* __restrict__ ei, int* __restrict__ cur,
                          int* __restrict__ perm){
  int e = blockIdx.x * 256 + threadIdx.x;
  if (e < NE){
    int p = atomicAdd(&cur[ei[e]], 1);
    perm[p] = e;
  }
}

// ---- shared GEMM inner loops: unrolled, depth-2 B-register prefetch ----
// frag(t,ks) at wp + (chbase + t*KST + ks)*512 + lane*8 ; A from LDS stride 328
__device__ __forceinline__ void gemm5(const unsigned short* __restrict__ s,
                                      const unsigned short* __restrict__ wp,
                                      int arow0, int arow1, int kl,
                                      int chbase, int lane, f32x4 (&acc)[2][5]){
  const unsigned short* wl0 = wp + (size_t)chbase * 512 + (size_t)lane * 8;
  bf16x8 b0[5], b1[5];
  #pragma unroll
  for (int t = 0; t < 5; t++) b0[t] = *(const bf16x8*)(wl0 + (t*10 + 0)*512);
  #pragma unroll
  for (int t = 0; t < 5; t++) b1[t] = *(const bf16x8*)(wl0 + (t*10 + 1)*512);
  #pragma unroll
  for (int ks = 0; ks < 10; ks++){
    bf16x8 a0 = *(const bf16x8*)(s + arow0*328 + ks*32 + kl);
    bf16x8 a1 = *(const bf16x8*)(s + arow1*328 + ks*32 + kl);
    bf16x8 cur[5];
    #pragma unroll
    for (int t = 0; t < 5; t++) cur[t] = (ks & 1) ? b1[t] : b0[t];
    if (ks < 8){
      #pragma unroll
      for (int t = 0; t < 5; t++){
        bf16x8 nv = *(const bf16x8*)(wl0 + (t*10 + ks + 2)*512);
        if (ks & 1) b1[t] = nv; else b0[t] = nv;
      }
    }
    #pragma unroll
    for (int t = 0; t < 5; t++){
      acc[0][t] = MFMA16(a0, cur[t], acc[0][t], 0, 0, 0);
      acc[1][t] = MFMA16(a1, cur[t], acc[1][t], 0, 0, 0);
    }
  }
}

// 10-wide variant (node kernel): one row-tile, 10 col-tiles, 10 ks with offset
__device__ __forceinline__ void gemm10(const unsigned short* __restrict__ s,
                                       const unsigned short* __restrict__ wp,
                                       int arow, int kl, int tbase, int kst,
                                       int ksoff, int lane, f32x4 (&acc)[10]){
  const unsigned short* wl0 = wp + (size_t)lane * 8;
  bf16x8 b0[10], b1[10];
  #pragma unroll
  for (int t = 0; t < 10; t++) b0[t] = *(const bf16x8*)(wl0 + (size_t)((tbase+t)*kst + ksoff)*512);
  #pragma unroll
  for (int t = 0; t < 10; t++) b1[t] = *(const bf16x8*)(wl0 + (size_t)((tbase+t)*kst + ksoff + 1)*512);
  #pragma unroll
  for (int ks = 0; ks < 10; ks++){
    bf16x8 a = *(const bf16x8*)(s + arow*328 + ks*32 + kl);
    bf16x8 cur[10];
    #pragma unroll
    for (int t = 0; t < 10; t++) cur[t] = (ks & 1) ? b1[t] : b0[t];
    if (ks < 8){
      #pragma unroll
      for (int t = 0; t < 10; t++){
        bf16x8 nv = *(const bf16x8*)(wl0 + (size_t)((tbase+t)*kst + ksoff + ks + 2)*512);
        if (ks & 1) b1[t] = nv; else b0[t] = nv;
      }
    }
    #pragma unroll
    for (int t = 0; t < 10; t++)
      acc[t] = MFMA16(a, cur[t], acc[t], 0, 0, 0);
  }
}

// ---------------- pre_gemm: P = h @ [W_r;W_c]^T  [NN x 640] bf16 ----------------
__global__ void __launch_bounds__(512, 4)
pre_gemm(const float* __restrict__ h, const unsigned short* __restrict__ Wsp,
         unsigned short* __restrict__ P){
  __shared__ __align__(16) unsigned short s_h[32*328];

  const int tid  = threadIdx.x;
  const int lane = tid & 63;
  const int ch   = tid >> 6;      // 0..7 -> cols ch*80..+79 of 640
  const int n0   = blockIdx.x * 32;

  const int arow0 = (lane & 15);
  const int arow1 = 16 + (lane & 15);
  const int kl = 8 * (lane >> 4);
  const int rb = (lane >> 4) * 4;

  // stage h (f32 -> bf16): 32 rows x 80 float4
  #pragma unroll
  for (int i = 0; i < 5; i++){
    int idx = tid + i*512;
    int r = idx / 80;
    int c = idx - r*80;
    int node = n0 + r;
    float4 v = (node < NN) ? *(const float4*)(h + (size_t)node*NFD + c*4)
                           : make_float4(0,0,0,0);
    unsigned int lo = (unsigned int)f2bf(v.x) | ((unsigned int)f2bf(v.y) << 16);
    unsigned int hi = (unsigned int)f2bf(v.z) | ((unsigned int)f2bf(v.w) << 16);
    *(uint2*)(s_h + r*328 + c*4) = make_uint2(lo, hi);
  }
  __syncthreads();

  f32x4 acc[2][5];
  #pragma unroll
  for (int rt = 0; rt < 2; rt++)
    #pragma unroll
    for (int t = 0; t < 5; t++) acc[rt][t] = {0.f,0.f,0.f,0.f};

  gemm5(s_h, Wsp, arow0, arow1, kl, ch*50, lane, acc);

  #pragma unroll
  for (int rt = 0; rt < 2; rt++){
    #pragma unroll
    for (int t = 0; t < 5; t++){
      int o = (ch*5 + t)*16 + (lane & 15);
      #pragma unroll
      for (int r = 0; r < 4; r++){
        int node = n0 + rt*16 + rb + r;
        if (node < NN) P[(size_t)node*640 + o] = f2bf(acc[rt][t][r]);
      }
    }
  }
}

// ---------------- edge kernel: 32 sorted edges/block, 256 threads ----------------
__global__ void __launch_bounds__(256, 3)
edge_kernel(const unsigned short* __restrict__ Pbf, const float* __restrict__ coord,
            const int* __restrict__ ei, const int* __restrict__ perm,
            const float* __restrict__ we1l, const float* __restrict__ be1,
            const unsigned short* __restrict__ We2p, const float* __restrict__ be2,
            const unsigned short* __restrict__ Wc1p, const float* __restrict__ bc1,
            const float* __restrict__ Wc2,
            unsigned short* __restrict__ agg, float* __restrict__ cacc)
{
  __shared__ __align__(16) unsigned short s_x[32*328]; // m2
  __shared__ __align__(16) unsigned short s_m[32*328]; // m1 / c1
  __shared__ float4 s_cd[32];
  __shared__ int s_row[32];
  __shared__ int s_col[32];
  __shared__ float s_w[32];

  const int tid  = threadIdx.x;
  const int lane = tid & 63;
  const int ch   = tid >> 6;     // 0..3 = column chunk (80 cols)
  const int e0   = blockIdx.x * 32;

  if (tid < 32){
    int e = perm[e0 + tid];
    int r = ei[e];
    int c = ei[NE + e];
    s_row[tid] = r; s_col[tid] = c;
    float dx = coord[r*3+0] - coord[c*3+0];
    float dy = coord[r*3+1] - coord[c*3+1];
    float dz = coord[r*3+2] - coord[c*3+2];
    float rad = dx*dx + dy*dy + dz*dz;
    float inv = 1.f / (sqrtf(rad) + 1e-8f);
    s_cd[tid] = make_float4(dx*inv, dy*inv, dz*inv, rad);
  }
  __syncthreads();

  const int arow0 = (lane & 15);
  const int arow1 = 16 + (lane & 15);
  const int kl = 8 * (lane >> 4);
  const int rb = (lane >> 4) * 4;

  // ---- m1 = silu(P_r[row] + P_c[col] + rad*wl + b) -> s_m ----
  #pragma unroll
  for (int i = 0; i < 5; i++){
    int idx = tid + i*256;
    int r = idx / 40;
    int c = idx - r*40;
    uint4 pr = *(const uint4*)(Pbf + (size_t)s_row[r]*640 + c*8);
    uint4 pc = *(const uint4*)(Pbf + (size_t)s_col[r]*640 + 320 + c*8);
    float4 bA = *(const float4*)(be1 + c*8);
    float4 bB = *(const float4*)(be1 + c*8 + 4);
    float4 wA = *(const float4*)(we1l + c*8);
    float4 wB = *(const float4*)(we1l + c*8 + 4);
    float rad = s_cd[r].w;
    float v0 = silu_f(bflo(pr.x) + bflo(pc.x) + rad*wA.x + bA.x);
    float v1 = silu_f(bfhi(pr.x) + bfhi(pc.x) + rad*wA.y + bA.y);
    float v2 = silu_f(bflo(pr.y) + bflo(pc.y) + rad*wA.z + bA.z);
    float v3 = silu_f(bfhi(pr.y) + bfhi(pc.y) + rad*wA.w + bA.w);
    float v4 = silu_f(bflo(pr.z) + bflo(pc.z) + rad*wB.x + bB.x);
    float v5 = silu_f(bfhi(pr.z) + bfhi(pc.z) + rad*wB.y + bB.y);
    float v6 = silu_f(bflo(pr.w) + bflo(pc.w) + rad*wB.z + bB.z);
    float v7 = silu_f(bfhi(pr.w) + bfhi(pc.w) + rad*wB.w + bB.w);
    uint4 q;
    q.x = (unsigned int)f2bf(v0) | ((unsigned int)f2bf(v1) << 16);
    q.y = (unsigned int)f2bf(v2) | ((unsigned int)f2bf(v3) << 16);
    q.z = (unsigned int)f2bf(v4) | ((unsigned int)f2bf(v5) << 16);
    q.w = (unsigned int)f2bf(v6) | ((unsigned int)f2bf(v7) << 16);
    *(uint4*)(s_m + r*328 + c*8) = q;
  }
  __syncthreads();

  f32x4 acc[2][5];

  // ---- L2: m2 = silu(m1 @ We2^T + be2) -> s_x ----
  #pragma unroll
  for (int rt = 0; rt < 2; rt++)
    #pragma unroll
    for (int t = 0; t < 5; t++) acc[rt][t] = {0.f,0.f,0.f,0.f};
  gemm5(s_m, We2p, arow0, arow1, kl, ch*50, lane, acc);
  #pragma unroll
  for (int rt = 0; rt < 2; rt++){
    #pragma unroll
    for (int t = 0; t < 5; t++){
      int o = (ch*5 + t)*16 + (lane & 15);
      float bb = be2[o];
      #pragma unroll
      for (int r = 0; r < 4; r++){
        int er = rt*16 + rb + r;
        s_x[er*328 + o] = f2bf(silu_f(acc[rt][t][r] + bb));
      }
    }
  }
  __syncthreads();

  // ---- c1 = silu(m2 @ Wc1^T + bc1) -> s_m ----
  #pragma unroll
  for (int rt = 0; rt < 2; rt++)
    #pragma unroll
    for (int t = 0; t < 5; t++) acc[rt][t] = {0.f,0.f,0.f,0.f};
  gemm5(s_x, Wc1p, arow0, arow1, kl, ch*50, lane, acc);
  #pragma unroll
  for (int rt = 0; rt < 2; rt++){
    #pragma unroll
    for (int t = 0; t < 5; t++){
      int o = (ch*5 + t)*16 + (lane & 15);
      float bb = bc1[o];
      #pragma unroll
      for (int r = 0; r < 4; r++){
        int er = rt*16 + rb + r;
        s_m[er*328 + o] = f2bf(silu_f(acc[rt][t][r] + bb));
      }
    }
  }
  __syncthreads();

  // ---- w = c1 . Wc2 (8 threads/edge) -> s_w ----
  {
    int e = tid >> 3;
    int j = tid & 7;
    const float* w8 = Wc2 + j*40;
    float sum = 0.f;
    #pragma unroll
    for (int u = 0; u < 5; u++){
      uint4 q = *(const uint4*)(s_m + e*328 + j*40 + u*8);
      const float* w = w8 + u*8;
      sum += bflo(q.x)*w[0] + bfhi(q.x)*w[1] + bflo(q.y)*w[2] + bfhi(q.y)*w[3]
           + bflo(q.z)*w[4] + bfhi(q.z)*w[5] + bflo(q.w)*w[6] + bfhi(q.w)*w[7];
    }
    sum += __shfl_xor(sum, 1);
    sum += __shfl_xor(sum, 2);
    sum += __shfl_xor(sum, 4);
    if (j == 0) s_w[e] = sum;
  }
  __syncthreads();

  // ---- segmented reduce of m2 (s_x, rows sorted) -> agg flush atomics ----
  if (tid < 160){
    int p = tid;
    float a0 = 0.f, a1 = 0.f;
    #pragma unroll
    for (int e = 0; e < 32; e++){
      unsigned int q = *(const unsigned int*)(s_x + e*328 + p*2);
      a0 += bflo(q); a1 += bfhi(q);
      if (e == 31 || s_row[e+1] != s_row[e]){
        unsigned int val = (unsigned int)f2bf(a0) | ((unsigned int)f2bf(a1) << 16);
        unsigned short* dst = agg + (size_t)s_row[e]*NFD + p*2;
        asm volatile("global_atomic_pk_add_bf16 %0, %1, off" :: "v"(dst), "v"(val) : "memory");
        a0 = 0.f; a1 = 0.f;
      }
    }
  }

  // ---- segmented reduce of coord trans ----
  if (tid >= 192 && tid < 195){
    int d = tid - 192;
    float a = 0.f;
    #pragma unroll
    for (int e = 0; e < 32; e++){
      float cdc = (d == 0) ? s_cd[e].x : (d == 1) ? s_cd[e].y : s_cd[e].z;
      a += cdc * s_w[e];
      if (e == 31 || s_row[e+1] != s_row[e]){
        atomicAdd(cacc + (size_t)s_row[e]*3 + d, a);
        a = 0.f;
      }
    }
  }
}

// ---------------- node kernel: 32 nodes/block, 256 threads ----------------
__global__ void __launch_bounds__(256, 3)
node_kernel(const float* __restrict__ h, const unsigned short* __restrict__ agg,
            const unsigned short* __restrict__ Wn1p, const float* __restrict__ bn1,
            const unsigned short* __restrict__ Wn2p, const float* __restrict__ bn2,
            float* __restrict__ hout)
{
  __shared__ __align__(16) unsigned short s_x[32*328];
  __shared__ __align__(16) unsigned short s_m[32*328];

  const int tid  = threadIdx.x;
  const int lane = tid & 63;
  const int wv   = tid >> 6;
  const int n0   = blockIdx.x * 32;

  const int rt = wv & 1;
  const int ch = wv >> 1;
  const int arow = rt*16 + (lane & 15);
  const int kl = 8 * (lane >> 4);
  const int colbase = ch * 160;
  const int rbase = rt*16 + (lane >> 4)*4;

  f32x4 acc[10];
  #pragma unroll
  for (int t = 0; t < 10; t++) acc[t] = {0.f,0.f,0.f,0.f};

  // ---- stage h (f32 -> bf16): 32 rows x 80 float4 ----
  #pragma unroll
  for (int i = 0; i < 10; i++){
    int idx = tid + i*256;
    int r = idx / 80;
    int c = idx - r*80;
    int node = n0 + r;
    float4 v = (node < NN) ? *(const float4*)(h + (size_t)node*NFD + c*4)
                           : make_float4(0,0,0,0);
    unsigned int lo = (unsigned int)f2bf(v.x) | ((unsigned int)f2bf(v.y) << 16);
    unsigned int hi = (unsigned int)f2bf(v.z) | ((unsigned int)f2bf(v.w) << 16);
    *(uint2*)(s_x + r*328 + c*4) = make_uint2(lo, hi);
  }
  __syncthreads();

  // ---- n1 half0 (h part): ks 0..9 ----
  gemm10(s_x, Wn1p, arow, kl, ch*10, 20, 0, lane, acc);
  __syncthreads();

  // ---- stage agg (bf16 copy): 32 rows x 40 uint4 ----
  #pragma unroll
  for (int i = 0; i < 5; i++){
    int idx = tid + i*256;
    int r = idx / 40;
    int c = idx - r*40;
    int node = n0 + r;
    uint4 v = (node < NN) ? *(const uint4*)(agg + (size_t)node*NFD + c*8)
                          : make_uint4(0,0,0,0);
    *(uint4*)(s_x + r*328 + c*8) = v;
  }
  __syncthreads();

  // ---- n1 half1 (agg part): ks 10..19, silu -> s_m ----
  gemm10(s_x, Wn1p, arow, kl, ch*10, 20, 10, lane, acc);
  #pragma unroll
  for (int t = 0; t < 10; t++){
    int o = colbase + t*16 + (lane & 15);
    float bb = bn1[o];
    #pragma unroll
    for (int r = 0; r < 4; r++)
      s_m[(rbase + r)*328 + o] = f2bf(silu_f(acc[t][r] + bb));
  }
  __syncthreads();

  // ---- n2: out = hid @ Wn2^T + bn2 + h (residual) ----
  #pragma unroll
  for (int t = 0; t < 10; t++) acc[t] = {0.f,0.f,0.f,0.f};
  gemm10(s_m, Wn2p, arow, kl, ch*10, 10, 0, lane, acc);
  #pragma unroll
  for (int t = 0; t < 10; t++){
    int o = colbase + t*16 + (lane & 15);
    float bb = bn2[o];
    #pragma unroll
    for (int r = 0; r < 4; r++){
      int node = n0 + rbase + r;
      if (node < NN)
        hout[(size_t)node*NFD + o] = h[(size_t)node*NFD + o] + acc[t][r] + bb;
    }
  }
}

extern "C" void kernel_launch(void* const* d_in, const int* in_sizes, int n_in,
                              void* d_out, int out_size, void* d_ws, size_t ws_size,
                              hipStream_t stream){
  const float* h     = (const float*)d_in[0];
  const float* coord = (const float*)d_in[1];
  const int*   ei    = (const int*)d_in[2];
  const float* We1 = (const float*)d_in[3];
  const float* be1 = (const float*)d_in[4];
  const float* We2 = (const float*)d_in[5];
  const float* be2 = (const float*)d_in[6];
  const float* Wn1 = (const float*)d_in[7];
  const float* bn1 = (const float*)d_in[8];
  const float* Wn2 = (const float*)d_in[9];
  const float* bn2 = (const float*)d_in[10];
  const float* Wc1 = (const float*)d_in[11];
  const float* bc1 = (const float*)d_in[12];
  const float* Wc2 = (const float*)d_in[13];

  char* ws = (char*)d_ws;
  unsigned short* We2p = (unsigned short*)(ws);             // 204800
  unsigned short* Wc1p = (unsigned short*)(ws + 204800);    // 204800
  unsigned short* Wn1p = (unsigned short*)(ws + 409600);    // 409600
  unsigned short* Wn2p = (unsigned short*)(ws + 819200);    // 204800
  unsigned short* Wsp  = (unsigned short*)(ws + 1024000);   // 409600
  float*          we1l = (float*)(ws + 1433600);            // 1280
  unsigned short* agg  = (unsigned short*)(ws + 1434880);   // 32,000,000
  int*            cnt  = (int*)(ws + 33434880);             // 200,000
  int*            cur  = (int*)(ws + 33634880);             // 200,000
  int*            perm = (int*)(ws + 33834880);             // 1,600,000
  int*            bsum = (int*)(ws + 35434880);             // 1,024

  float* hout = (float*)d_out;
  float* cout = hout + (size_t)NN * NFD;        // coord output region
  // P lives in the (dead until node_kernel writes it) hout region: exactly 64 MB
  unsigned short* Pbf = (unsigned short*)d_out;

  hipMemsetAsync(agg, 0, (size_t)NN * NFD * 2, stream);
  hipMemsetAsync(cnt, 0, (size_t)NN * 4, stream);

  cinit<<<(NN*3 + 255)/256, 256, 0, stream>>>(coord, cout);

  pack_w<<< 50, 256, 0, stream>>>(We2, We2p, 320, 10);
  pack_w<<< 50, 256, 0, stream>>>(Wc1, Wc1p, 320, 10);
  pack_w<<<100, 256, 0, stream>>>(Wn1, Wn1p, 640, 20);
  pack_w<<< 50, 256, 0, stream>>>(Wn2, Wn2p, 320, 10);
  pack_stack<<<100, 256, 0, stream>>>(We1, Wsp);
  extract_last<<<1, 320, 0, stream>>>(We1, we1l);

  hist_k<<<(NE + 255)/256, 256, 0, stream>>>(ei, cnt);
  scan1<<<NB1, 256, 0, stream>>>(cnt, cur, bsum);
  scan2<<<1, 256, 0, stream>>>(bsum);
  scan3<<<NB1, 256, 0, stream>>>(cur, bsum);
  scatter_k<<<(NE + 255)/256, 256, 0, stream>>>(ei, cur, perm);

  pre_gemm<<<(NN + 31)/32, 512, 0, stream>>>(h, Wsp, Pbf);

  edge_kernel<<<NE/32, 256, 0, stream>>>(Pbf, coord, ei, perm, we1l, be1,
                                         We2p, be2, Wc1p, bc1, Wc2, agg, cout);
  node_kernel<<<(NN + 31)/32, 256, 0, stream>>>(h, agg, Wn1p, bn1, Wn2p, bn2, hout);
}